// Round 1
// baseline (214.746 us; speedup 1.0000x reference)
//
#include <hip/hip_runtime.h>

// ---- cross-lane helpers (ds_swizzle BitMode: new_lane = ((lane & and) | or) ^ xor) ----
#define SWZ(v, imm) __int_as_float(__builtin_amdgcn_ds_swizzle(__float_as_int(v), (imm)))
// broadcast lane (group8_base + k) to all 8 lanes of the group: and=0x18 (keep bits 4:3), or=k
#define BCAST(v, k) SWZ(v, (((k) << 5) | 0x18))
#define BCAST8(dst, v)                                                         \
    dst[0] = BCAST(v, 0); dst[1] = BCAST(v, 1); dst[2] = BCAST(v, 2);          \
    dst[3] = BCAST(v, 3); dst[4] = BCAST(v, 4); dst[5] = BCAST(v, 5);          \
    dst[6] = BCAST(v, 6); dst[7] = BCAST(v, 7);
// xor-butterfly within 8-lane group (masks 1,2,4)
#define RXOR(v, m) SWZ(v, (((m) << 10) | 0x1F))

__device__ __forceinline__ float fast_sig(float x) {
    // sigmoid(x) = 1/(1+2^(-x*log2e)) ; exp2 saturates to 0/inf safely
    float e = __builtin_amdgcn_exp2f(-1.44269504088896340736f * x);
    return __builtin_amdgcn_rcpf(1.0f + e);
}
__device__ __forceinline__ float fast_tanh(float x) {
    // tanh(x) = 1 - 2/(2^(2x*log2e)+1) ; +/-inf-safe -> +/-1
    float e = __builtin_amdgcn_exp2f(2.88539008177792681472f * x);
    return 1.0f - 2.0f * __builtin_amdgcn_rcpf(e + 1.0f);
}

constexpr int T_STEPS = 49;

__global__ __launch_bounds__(256) void lstm2_kernel(
    const float* __restrict__ X,
    const float* __restrict__ W_ih0, const float* __restrict__ W_hh0,
    const float* __restrict__ b_ih0, const float* __restrict__ b_hh0,
    const float* __restrict__ W_ih1, const float* __restrict__ W_hh1,
    const float* __restrict__ b_ih1, const float* __restrict__ b_hh1,
    const float* __restrict__ W_lin, const float* __restrict__ b_lin,
    float* __restrict__ out, int Bn)
{
    const int tid = blockIdx.x * 256 + threadIdx.x;
    const int b   = tid >> 3;            // batch element (8 lanes per element)
    const int j   = threadIdx.x & 7;     // hidden unit owned by this lane

    if (b >= Bn) return;

    // ---- weights into registers: lane j holds rows {j, 8+j, 16+j, 24+j} (i,f,g,o) ----
    float wx0[4], bb0[4], bb1[4];
    float whh0[4][8], wi1[4][8], whh1[4][8];
#pragma unroll
    for (int g = 0; g < 4; ++g) {
        const int r = g * 8 + j;
        wx0[g] = W_ih0[r];
        bb0[g] = b_ih0[r] + b_hh0[r];
        bb1[g] = b_ih1[r] + b_hh1[r];
#pragma unroll
        for (int k = 0; k < 8; ++k) {
            whh0[g][k] = W_hh0[r * 8 + k];
            wi1[g][k]  = W_ih1[r * 8 + k];
            whh1[g][k] = W_hh1[r * 8 + k];
        }
    }
    const float wlin = W_lin[j];
    const float blin = b_lin[0];

    float h1 = 0.f, c1 = 0.f, h2 = 0.f, c2 = 0.f;
    float h1b[8], h2b[8];
#pragma unroll
    for (int k = 0; k < 8; ++k) { h1b[k] = 0.f; h2b[k] = 0.f; }

    const float* xp = X + (long long)b * T_STEPS;

#pragma unroll 1
    for (int t = 0; t < T_STEPS; ++t) {
        const float x = xp[t];

        // ---- layer 1: a = x*W_ih0 + (b_ih0+b_hh0) + W_hh0 @ h1(t-1) ----
        // h1b holds h1(t-1) broadcast (set at end of previous iteration)
        float a[4];
#pragma unroll
        for (int g = 0; g < 4; ++g) {
            a[g] = fmaf(x, wx0[g], bb0[g]);
#pragma unroll
            for (int k = 0; k < 8; ++k) a[g] = fmaf(whh0[g][k], h1b[k], a[g]);
        }
        float gi = fast_sig(a[0]);
        float gf = fast_sig(a[1]);
        float gg = fast_tanh(a[2]);
        float go = fast_sig(a[3]);
        c1 = fmaf(gf, c1, gi * gg);
        h1 = go * fast_tanh(c1);

        // broadcast new h1 (layer-2 input now, layer-1 recurrent input next step)
        // and old h2 (layer-2 recurrent input)
        BCAST8(h1b, h1);
        BCAST8(h2b, h2);

        // ---- layer 2: a2 = W_ih1 @ h1(t) + (b_ih1+b_hh1) + W_hh1 @ h2(t-1) ----
        float a2[4];
#pragma unroll
        for (int g = 0; g < 4; ++g) {
            a2[g] = bb1[g];
#pragma unroll
            for (int k = 0; k < 8; ++k) a2[g] = fmaf(wi1[g][k], h1b[k], a2[g]);
#pragma unroll
            for (int k = 0; k < 8; ++k) a2[g] = fmaf(whh1[g][k], h2b[k], a2[g]);
        }
        gi = fast_sig(a2[0]);
        gf = fast_sig(a2[1]);
        gg = fast_tanh(a2[2]);
        go = fast_sig(a2[3]);
        c2 = fmaf(gf, c2, gi * gg);
        h2 = go * fast_tanh(c2);
    }

    // ---- epilogue: relu -> linear(H->1) -> relu, lane 0 of each group writes ----
    float v = fmaxf(h2, 0.f) * wlin;
    v += RXOR(v, 1);
    v += RXOR(v, 2);
    v += RXOR(v, 4);
    if (j == 0) out[b] = fmaxf(v + blin, 0.f);
}

extern "C" void kernel_launch(void* const* d_in, const int* in_sizes, int n_in,
                              void* d_out, int out_size, void* d_ws, size_t ws_size,
                              hipStream_t stream) {
    const float* X     = (const float*)d_in[0];
    const float* W_ih0 = (const float*)d_in[1];
    const float* W_hh0 = (const float*)d_in[2];
    const float* b_ih0 = (const float*)d_in[3];
    const float* b_hh0 = (const float*)d_in[4];
    const float* W_ih1 = (const float*)d_in[5];
    const float* W_hh1 = (const float*)d_in[6];
    const float* b_ih1 = (const float*)d_in[7];
    const float* b_hh1 = (const float*)d_in[8];
    const float* W_lin = (const float*)d_in[9];
    const float* b_lin = (const float*)d_in[10];
    float* out = (float*)d_out;

    const int Bn = in_sizes[0] / T_STEPS;       // 131072
    const int threads = Bn * 8;                 // 8 lanes per batch element
    const int block = 256;
    const int grid = (threads + block - 1) / block;

    lstm2_kernel<<<grid, block, 0, stream>>>(X, W_ih0, W_hh0, b_ih0, b_hh0,
                                             W_ih1, W_hh1, b_ih1, b_hh1,
                                             W_lin, b_lin, out, Bn);
}

// Round 2
// 193.903 us; speedup vs baseline: 1.1075x; 1.1075x over previous
//
#include <hip/hip_runtime.h>

typedef float f2 __attribute__((ext_vector_type(2)));

// ---- cross-lane helpers (ds_swizzle BitMode: new_lane = ((lane & and) | or) ^ xor) ----
#define SWZ(v, imm) __int_as_float(__builtin_amdgcn_ds_swizzle(__float_as_int(v), (imm)))
// broadcast lane (group8_base + k) to all 8 lanes of the group: and=0x18, or=k
#define BCAST(v, k) SWZ(v, (((k) << 5) | 0x18))
// xor-butterfly within 8-lane group
#define RXOR(v, m) SWZ(v, (((m) << 10) | 0x1F))

// ---- packed fp32 (VOP3P) helpers; op_sel word-select broadcasts one weight to both halves ----
__device__ __forceinline__ f2 pk_fma(f2 a, f2 b, f2 c) {
    f2 d; asm("v_pk_fma_f32 %0, %1, %2, %3" : "=v"(d) : "v"(a), "v"(b), "v"(c)); return d;
}
__device__ __forceinline__ f2 pk_fma_lo(f2 w, f2 h, f2 c) {  // w.x used for both halves
    f2 d; asm("v_pk_fma_f32 %0, %1, %2, %3 op_sel:[0,0,0] op_sel_hi:[0,1,1]"
              : "=v"(d) : "v"(w), "v"(h), "v"(c)); return d;
}
__device__ __forceinline__ f2 pk_fma_hi(f2 w, f2 h, f2 c) {  // w.y used for both halves
    f2 d; asm("v_pk_fma_f32 %0, %1, %2, %3 op_sel:[1,0,0] op_sel_hi:[1,1,1]"
              : "=v"(d) : "v"(w), "v"(h), "v"(c)); return d;
}
__device__ __forceinline__ f2 pk_mul(f2 a, f2 b) {
    f2 d; asm("v_pk_mul_f32 %0, %1, %2" : "=v"(d) : "v"(a), "v"(b)); return d;
}
__device__ __forceinline__ f2 pk_add(f2 a, f2 b) {
    f2 d; asm("v_pk_add_f32 %0, %1, %2" : "=v"(d) : "v"(a), "v"(b)); return d;
}

// sigmoid(x) = 1/(1+2^(-x*log2e)) — op-for-op identical per half to the scalar round-1 version
__device__ __forceinline__ f2 sig2(f2 x) {
    const f2 nl2e = { -1.44269504088896340736f, -1.44269504088896340736f };
    const f2 one2 = { 1.0f, 1.0f };
    f2 m = pk_mul(x, nl2e);
    f2 e; e.x = __builtin_amdgcn_exp2f(m.x); e.y = __builtin_amdgcn_exp2f(m.y);
    f2 s = pk_add(e, one2);
    f2 r; r.x = __builtin_amdgcn_rcpf(s.x); r.y = __builtin_amdgcn_rcpf(s.y);
    return r;
}
// tanh(x) = 1 - 2/(2^(2x*log2e)+1); fma(-2,r,1) == 1-2r bitwise (2r exact)
__device__ __forceinline__ f2 tanh2(f2 x) {
    const f2 p2l2e = { 2.88539008177792681472f, 2.88539008177792681472f };
    const f2 one2  = { 1.0f, 1.0f };
    const f2 neg22 = { -2.0f, -2.0f };
    f2 m = pk_mul(x, p2l2e);
    f2 e; e.x = __builtin_amdgcn_exp2f(m.x); e.y = __builtin_amdgcn_exp2f(m.y);
    f2 s = pk_add(e, one2);
    f2 r; r.x = __builtin_amdgcn_rcpf(s.x); r.y = __builtin_amdgcn_rcpf(s.y);
    return pk_fma(r, neg22, one2);
}

constexpr int T_STEPS = 49;

// 8 lanes per 2 batch elements: lane j owns hidden unit j for elements (2q, 2q+1),
// packed in the (lo,hi) halves of f2 registers. Weights stored once as f2 pairs
// over k; op_sel broadcast selects the word -> no weight duplication.
__global__ __launch_bounds__(256, 2) void lstm2_kernel(
    const float* __restrict__ X,
    const float* __restrict__ W_ih0, const float* __restrict__ W_hh0,
    const float* __restrict__ b_ih0, const float* __restrict__ b_hh0,
    const float* __restrict__ W_ih1, const float* __restrict__ W_hh1,
    const float* __restrict__ b_ih1, const float* __restrict__ b_hh1,
    const float* __restrict__ W_lin, const float* __restrict__ b_lin,
    float* __restrict__ out, int nq)   // nq = B/2
{
    const int tid = blockIdx.x * 256 + threadIdx.x;
    const int q   = tid >> 3;            // pair index (2 batch elements)
    const int j   = threadIdx.x & 7;     // hidden unit owned by this lane
    if (q >= nq) return;

    // ---- weights: lane j holds rows {j, 8+j, 16+j, 24+j} (i,f,g,o), k-pairs as f2 ----
    f2 whh0p[4][4], wi1p[4][4], whh1p[4][4];
    f2 bb0d[4], bb1d[4];
#pragma unroll
    for (int g = 0; g < 4; ++g) {
        const int r = g * 8 + j;
        const f2* w0 = (const f2*)(W_hh0 + r * 8);
        const f2* w1 = (const f2*)(W_ih1 + r * 8);
        const f2* w2 = (const f2*)(W_hh1 + r * 8);
#pragma unroll
        for (int kp = 0; kp < 4; ++kp) {
            whh0p[g][kp] = w0[kp];
            wi1p[g][kp]  = w1[kp];
            whh1p[g][kp] = w2[kp];
        }
        float b0 = b_ih0[r] + b_hh0[r];  bb0d[g].x = b0; bb0d[g].y = b0;
        float b1 = b_ih1[r] + b_hh1[r];  bb1d[g].x = b1; bb1d[g].y = b1;
    }
    f2 wx0p0, wx0p1;   // W_ih0 rows (gates 0,1) and (2,3) for unit j
    wx0p0.x = W_ih0[0 * 8 + j];  wx0p0.y = W_ih0[1 * 8 + j];
    wx0p1.x = W_ih0[2 * 8 + j];  wx0p1.y = W_ih0[3 * 8 + j];
    const float wlin = W_lin[j];
    const float blin = b_lin[0];

    f2 h1, c1, h2, c2;
    h1 = 0.f; c1 = 0.f; h2 = 0.f; c2 = 0.f;
    f2 h1b[8], h2b[8];
#pragma unroll
    for (int k = 0; k < 8; ++k) { h1b[k] = 0.f; h2b[k] = 0.f; }

    const float* xp0 = X + (long long)(2 * q) * T_STEPS;
    const float* xp1 = xp0 + T_STEPS;

#pragma unroll 1
    for (int t = 0; t < T_STEPS; ++t) {
        f2 x2; x2.x = xp0[t]; x2.y = xp1[t];

        // ---- layer 1: a = x*W_ih0 + (b_ih0+b_hh0) + W_hh0 @ h1(t-1) ----
        f2 a[4];
        a[0] = pk_fma_lo(wx0p0, x2, bb0d[0]);
        a[1] = pk_fma_hi(wx0p0, x2, bb0d[1]);
        a[2] = pk_fma_lo(wx0p1, x2, bb0d[2]);
        a[3] = pk_fma_hi(wx0p1, x2, bb0d[3]);
#pragma unroll
        for (int g = 0; g < 4; ++g) {
#pragma unroll
            for (int kp = 0; kp < 4; ++kp) {
                a[g] = pk_fma_lo(whh0p[g][kp], h1b[2 * kp],     a[g]);
                a[g] = pk_fma_hi(whh0p[g][kp], h1b[2 * kp + 1], a[g]);
            }
        }
        f2 gi = sig2(a[0]);
        f2 gf = sig2(a[1]);
        f2 gg = tanh2(a[2]);
        f2 go = sig2(a[3]);
        c1 = pk_fma(gf, c1, pk_mul(gi, gg));
        h1 = pk_mul(go, tanh2(c1));

        // broadcast new h1 (layer-2 input now, layer-1 recurrent next step) and old h2
        h1b[0].x = BCAST(h1.x, 0); h1b[0].y = BCAST(h1.y, 0);
        h1b[1].x = BCAST(h1.x, 1); h1b[1].y = BCAST(h1.y, 1);
        h1b[2].x = BCAST(h1.x, 2); h1b[2].y = BCAST(h1.y, 2);
        h1b[3].x = BCAST(h1.x, 3); h1b[3].y = BCAST(h1.y, 3);
        h1b[4].x = BCAST(h1.x, 4); h1b[4].y = BCAST(h1.y, 4);
        h1b[5].x = BCAST(h1.x, 5); h1b[5].y = BCAST(h1.y, 5);
        h1b[6].x = BCAST(h1.x, 6); h1b[6].y = BCAST(h1.y, 6);
        h1b[7].x = BCAST(h1.x, 7); h1b[7].y = BCAST(h1.y, 7);
        h2b[0].x = BCAST(h2.x, 0); h2b[0].y = BCAST(h2.y, 0);
        h2b[1].x = BCAST(h2.x, 1); h2b[1].y = BCAST(h2.y, 1);
        h2b[2].x = BCAST(h2.x, 2); h2b[2].y = BCAST(h2.y, 2);
        h2b[3].x = BCAST(h2.x, 3); h2b[3].y = BCAST(h2.y, 3);
        h2b[4].x = BCAST(h2.x, 4); h2b[4].y = BCAST(h2.y, 4);
        h2b[5].x = BCAST(h2.x, 5); h2b[5].y = BCAST(h2.y, 5);
        h2b[6].x = BCAST(h2.x, 6); h2b[6].y = BCAST(h2.y, 6);
        h2b[7].x = BCAST(h2.x, 7); h2b[7].y = BCAST(h2.y, 7);

        // ---- layer 2: a2 = W_ih1 @ h1(t) + (b_ih1+b_hh1) + W_hh1 @ h2(t-1) ----
        f2 a2[4];
#pragma unroll
        for (int g = 0; g < 4; ++g) {
            a2[g] = bb1d[g];
#pragma unroll
            for (int kp = 0; kp < 4; ++kp) {
                a2[g] = pk_fma_lo(wi1p[g][kp], h1b[2 * kp],     a2[g]);
                a2[g] = pk_fma_hi(wi1p[g][kp], h1b[2 * kp + 1], a2[g]);
            }
#pragma unroll
            for (int kp = 0; kp < 4; ++kp) {
                a2[g] = pk_fma_lo(whh1p[g][kp], h2b[2 * kp],     a2[g]);
                a2[g] = pk_fma_hi(whh1p[g][kp], h2b[2 * kp + 1], a2[g]);
            }
        }
        gi = sig2(a2[0]);
        gf = sig2(a2[1]);
        gg = tanh2(a2[2]);
        go = sig2(a2[3]);
        c2 = pk_fma(gf, c2, pk_mul(gi, gg));
        h2 = pk_mul(go, tanh2(c2));
    }

    // ---- epilogue: relu -> linear(H->1) -> relu; lane 0 writes both elements ----
    float vx = fmaxf(h2.x, 0.f) * wlin;
    float vy = fmaxf(h2.y, 0.f) * wlin;
    vx += RXOR(vx, 1); vy += RXOR(vy, 1);
    vx += RXOR(vx, 2); vy += RXOR(vy, 2);
    vx += RXOR(vx, 4); vy += RXOR(vy, 4);
    if (j == 0) {
        f2 o; o.x = fmaxf(vx + blin, 0.f); o.y = fmaxf(vy + blin, 0.f);
        *(f2*)(out + 2 * (long long)q) = o;
    }
}

extern "C" void kernel_launch(void* const* d_in, const int* in_sizes, int n_in,
                              void* d_out, int out_size, void* d_ws, size_t ws_size,
                              hipStream_t stream) {
    const float* X     = (const float*)d_in[0];
    const float* W_ih0 = (const float*)d_in[1];
    const float* W_hh0 = (const float*)d_in[2];
    const float* b_ih0 = (const float*)d_in[3];
    const float* b_hh0 = (const float*)d_in[4];
    const float* W_ih1 = (const float*)d_in[5];
    const float* W_hh1 = (const float*)d_in[6];
    const float* b_ih1 = (const float*)d_in[7];
    const float* b_hh1 = (const float*)d_in[8];
    const float* W_lin = (const float*)d_in[9];
    const float* b_lin = (const float*)d_in[10];
    float* out = (float*)d_out;

    const int Bn = in_sizes[0] / T_STEPS;   // 131072
    const int nq = Bn >> 1;                 // 2 elements per 8-lane group
    const int threads = nq * 8;
    const int block = 256;
    const int grid = (threads + block - 1) / block;

    lstm2_kernel<<<grid, block, 0, stream>>>(X, W_ih0, W_hh0, b_ih0, b_hh0,
                                             W_ih1, W_hh1, b_ih1, b_hh1,
                                             W_lin, b_lin, out, nq);
}